// Round 1
// baseline (360.376 us; speedup 1.0000x reference)
//
#include <hip/hip_runtime.h>

// SLAYER MLP forward: spike(psp(W2 @ spike(psp(W1 @ x))))
// B=256, IN=78, HID=16, OUT=20, T=1000, K=100 (SRM alpha kernel, tau=10)
//
// Numerics: output is binary threshold (u >= 1.0), so we compute u as close
// to the exact value as possible: fp64 accumulation in both matmul and FIR,
// with fp32 rounding applied exactly where the reference materializes
// intermediates (einsum result z, and final u before comparison).

#define B_    256
#define IN_   78
#define HID_  16
#define OUT_  20
#define T_    1000
#define K_    100
#define TT_   125                 // timesteps per tile (1000 = 8 * 125)
#define NTILE_ 8
#define J_    (TT_ + K_ - 1)      // 224: tile + left halo
#define ICH_  39                  // input-channel chunk (78 = 2 * 39)

__global__ __launch_bounds__(256) void slayer_l1(
    const float* __restrict__ x,    // [B, IN, T]
    const float* __restrict__ W1,   // [HID, IN]
    float* __restrict__ s1)         // [B, HID, T] spikes (0/1 float)
{
    __shared__ float xs[ICH_][J_];   // 34,944 B
    __shared__ float zs[HID_][J_];   // 14,336 B
    __shared__ float w[HID_][IN_];   //  4,992 B
    __shared__ float eps[K_];        //    400 B   total 54,672 B

    const int tid  = threadIdx.x;
    const int b    = blockIdx.x / NTILE_;
    const int tile = blockIdx.x % NTILE_;
    const int t0   = tile * TT_;

    for (int idx = tid; idx < HID_ * IN_; idx += 256)
        w[idx / IN_][idx % IN_] = W1[idx];
    if (tid < K_) {
        float a = (float)tid / 10.0f;          // t / tau, mirrors reference fp32 ops
        eps[tid] = a * expf(1.0f - a);
    }

    // per-thread fp64 accumulators: HID_*J_ = 3584 = 14 * 256 exactly
    double acc[14];
#pragma unroll
    for (int k = 0; k < 14; ++k) acc[k] = 0.0;

    // matmul z[h][j] = sum_i W1[h][i] * x[b][i][t0-99+j], chunked over i
    for (int c = 0; c < 2; ++c) {
        __syncthreads();
        for (int idx = tid; idx < ICH_ * J_; idx += 256) {
            int i = idx / J_, j = idx % J_;
            int t = t0 - (K_ - 1) + j;
            xs[i][j] = (t >= 0) ? x[((size_t)b * IN_ + (c * ICH_ + i)) * (size_t)T_ + t]
                                : 0.0f;
        }
        __syncthreads();
#pragma unroll
        for (int k = 0; k < 14; ++k) {
            int idx = tid + k * 256;
            int h = idx / J_, j = idx % J_;
            double a = 0.0;
#pragma unroll
            for (int i = 0; i < ICH_; ++i)
                a += (double)w[h][c * ICH_ + i] * (double)xs[i][j];
            acc[k] += a;
        }
    }
    __syncthreads();
#pragma unroll
    for (int k = 0; k < 14; ++k) {
        int idx = tid + k * 256;
        zs[idx / J_][idx % J_] = (float)acc[k];   // fp32 rounding, like reference einsum output
    }
    __syncthreads();

    // causal FIR + threshold: u[t] = sum_s eps[s] * z[t - s]
    for (int idx = tid; idx < HID_ * TT_; idx += 256) {
        int h = idx / TT_, tt = idx % TT_;
        double u = 0.0;
#pragma unroll 4
        for (int s = 0; s < K_; ++s)
            u += (double)eps[s] * (double)zs[h][tt + (K_ - 1) - s];
        float uf = (float)u;                      // fp32 rounding before compare, like reference
        s1[((size_t)b * HID_ + h) * (size_t)T_ + (t0 + tt)] = (uf >= 1.0f) ? 1.0f : 0.0f;
    }
}

__global__ __launch_bounds__(256) void slayer_l2(
    const float* __restrict__ s1,   // [B, HID, T]
    const float* __restrict__ W2,   // [OUT, HID]
    float* __restrict__ out)        // [B, OUT, T]
{
    __shared__ float ss[HID_][J_];   // 14,336 B
    __shared__ float zs[OUT_][J_];   // 17,920 B
    __shared__ float w[OUT_][HID_];  //  1,280 B
    __shared__ float eps[K_];        //    400 B   total 33,936 B

    const int tid  = threadIdx.x;
    const int b    = blockIdx.x / NTILE_;
    const int tile = blockIdx.x % NTILE_;
    const int t0   = tile * TT_;

    for (int idx = tid; idx < OUT_ * HID_; idx += 256)
        w[idx / HID_][idx % HID_] = W2[idx];
    if (tid < K_) {
        float a = (float)tid / 10.0f;
        eps[tid] = a * expf(1.0f - a);
    }

    for (int idx = tid; idx < HID_ * J_; idx += 256) {
        int h = idx / J_, j = idx % J_;
        int t = t0 - (K_ - 1) + j;
        ss[h][j] = (t >= 0) ? s1[((size_t)b * HID_ + h) * (size_t)T_ + t] : 0.0f;
    }
    __syncthreads();

    for (int idx = tid; idx < OUT_ * J_; idx += 256) {
        int o = idx / J_, j = idx % J_;
        double a = 0.0;
#pragma unroll
        for (int h = 0; h < HID_; ++h)
            a += (double)w[o][h] * (double)ss[h][j];
        zs[o][j] = (float)a;
    }
    __syncthreads();

    for (int idx = tid; idx < OUT_ * TT_; idx += 256) {
        int o = idx / TT_, tt = idx % TT_;
        double u = 0.0;
#pragma unroll 4
        for (int s = 0; s < K_; ++s)
            u += (double)eps[s] * (double)zs[o][tt + (K_ - 1) - s];
        float uf = (float)u;
        out[((size_t)b * OUT_ + o) * (size_t)T_ + (t0 + tt)] = (uf >= 1.0f) ? 1.0f : 0.0f;
    }
}

extern "C" void kernel_launch(void* const* d_in, const int* in_sizes, int n_in,
                              void* d_out, int out_size, void* d_ws, size_t ws_size,
                              hipStream_t stream) {
    const float* x  = (const float*)d_in[0];   // spike_input [256, 78, 1000]
    const float* W1 = (const float*)d_in[1];   // [16, 78]
    const float* W2 = (const float*)d_in[2];   // [20, 16]
    float* out = (float*)d_out;                // [256, 20, 1000]
    float* s1  = (float*)d_ws;                 // [256, 16, 1000] = 16.384 MB scratch

    dim3 grid(B_ * NTILE_);
    dim3 block(256);
    slayer_l1<<<grid, block, 0, stream>>>(x, W1, s1);
    slayer_l2<<<grid, block, 0, stream>>>(s1, W2, out);
}